// Round 1
// baseline (1346.476 us; speedup 1.0000x reference)
//
#include <hip/hip_runtime.h>
#include <hip/hip_bf16.h>
#include <cstdint>
#include <cstddef>

#define NN 4096
#define ITERS 50

// ---------------------------------------------------------------------------
// Sinkhorn in linear space.
//   E = exp(M); rc[j] = 1/c_sum[j]; rr[i] = 1/r_sum[i]
//   row: r_sum[i] = sum_j E[i,j]*rc[j]
//   col: c_sum[j] = sum_i E[i,j]*rr[i]
//   out = max(E[i,j]*rr[i]*rc[j], 1e-9)
// ---------------------------------------------------------------------------

__global__ __launch_bounds__(256) void sk_init(float* __restrict__ rc,
                                               float* __restrict__ c_sum) {
    int j = blockIdx.x * 256 + threadIdx.x;
    rc[j] = 1.0f;      // c = 0 initially -> multiplier 1
    c_sum[j] = 0.0f;   // zero accumulator for first col pass
}

__global__ __launch_bounds__(256) void sk_exp(const float* __restrict__ M,
                                              float* __restrict__ E) {
    size_t idx = ((size_t)blockIdx.x * 256 + threadIdx.x) * 4;
    float4 m = *(const float4*)(M + idx);
    float4 e;
    e.x = __expf(m.x); e.y = __expf(m.y); e.z = __expf(m.z); e.w = __expf(m.w);
    *(float4*)(E + idx) = e;
}

// One wave (64 lanes) per row; 4 rows per 256-thread block; grid = 1024 blocks.
template<bool HAS_E>
__global__ __launch_bounds__(256) void sk_row(const float* __restrict__ Mat,
                                              const float* __restrict__ rc,
                                              float* __restrict__ rr) {
    const int wave = threadIdx.x >> 6;
    const int lane = threadIdx.x & 63;
    const int row  = blockIdx.x * 4 + wave;
    const float4* __restrict__ Mrow = (const float4*)(Mat + (size_t)row * NN);
    const float4* __restrict__ RC   = (const float4*)rc;
    float s = 0.0f;
    #pragma unroll 4
    for (int k = lane; k < NN / 4; k += 64) {
        float4 m = Mrow[k];
        float4 c = RC[k];
        if (!HAS_E) {
            m.x = __expf(m.x); m.y = __expf(m.y);
            m.z = __expf(m.z); m.w = __expf(m.w);
        }
        s += m.x * c.x + m.y * c.y + m.z * c.z + m.w * c.w;
    }
    #pragma unroll
    for (int off = 32; off > 0; off >>= 1) s += __shfl_down(s, off, 64);
    if (lane == 0) rr[row] = 1.0f / s;
}

// Grid (16 col-blocks, 64 row-blocks); each block: 256 cols x 64 rows,
// coalesced row-major reads, one atomicAdd per (block, col).
template<bool HAS_E>
__global__ __launch_bounds__(256) void sk_col(const float* __restrict__ Mat,
                                              const float* __restrict__ rr,
                                              float* __restrict__ c_sum) {
    const int j  = blockIdx.x * 256 + threadIdx.x;
    const int r0 = blockIdx.y * 64;
    const float* __restrict__ rrp = rr + r0;
    const float* __restrict__ p   = Mat + (size_t)r0 * NN + j;
    float s = 0.0f;
    #pragma unroll 8
    for (int i = 0; i < 64; ++i) {
        float m = p[(size_t)i * NN];
        if (!HAS_E) m = __expf(m);
        s += m * rrp[i];   // rrp[i] is block-uniform -> scalar load
    }
    atomicAdd(&c_sum[j], s);
}

__global__ __launch_bounds__(256) void sk_recip(float* __restrict__ c_sum,
                                                float* __restrict__ rc) {
    int j = blockIdx.x * 256 + threadIdx.x;
    rc[j] = 1.0f / c_sum[j];
    c_sum[j] = 0.0f;   // ready for next col pass
}

template<bool HAS_E>
__global__ __launch_bounds__(256) void sk_final(const float* __restrict__ Mat,
                                                const float* __restrict__ rr,
                                                const float* __restrict__ rc,
                                                float* __restrict__ out) {
    const int row = blockIdx.y;
    const int c4  = blockIdx.x * 256 + threadIdx.x;   // 0..1023 (float4 index)
    float4 m = ((const float4*)(Mat + (size_t)row * NN))[c4];
    if (!HAS_E) {
        m.x = __expf(m.x); m.y = __expf(m.y);
        m.z = __expf(m.z); m.w = __expf(m.w);
    }
    float4 c = ((const float4*)rc)[c4];
    float  r = rr[row];
    float4 o;
    o.x = fmaxf(m.x * r * c.x, 1e-9f);
    o.y = fmaxf(m.y * r * c.y, 1e-9f);
    o.z = fmaxf(m.z * r * c.z, 1e-9f);
    o.w = fmaxf(m.w * r * c.w, 1e-9f);
    ((float4*)out)[(size_t)row * (NN / 4) + c4] = o;
}

extern "C" void kernel_launch(void* const* d_in, const int* in_sizes, int n_in,
                              void* d_out, int out_size, void* d_ws, size_t ws_size,
                              hipStream_t stream) {
    const float* M   = (const float*)d_in[0];
    float*       out = (float*)d_out;
    char*        ws  = (char*)d_ws;

    float* rc    = (float*)(ws);                // 16 KiB
    float* rr    = (float*)(ws + 16 * 1024);    // 16 KiB
    float* c_sum = (float*)(ws + 32 * 1024);    // 16 KiB
    float* E     = (float*)(ws + 64 * 1024);    // 64 MiB (optional)

    const size_t need_e = 64 * 1024 + (size_t)NN * NN * sizeof(float);
    const bool   has_e  = ws_size >= need_e;

    sk_init<<<NN / 256, 256, 0, stream>>>(rc, c_sum);

    const float* Mat = M;
    if (has_e) {
        sk_exp<<<(NN * (size_t)NN) / 1024, 256, 0, stream>>>(M, E);
        Mat = E;
    }

    dim3 gcol(16, 64);
    for (int it = 0; it < ITERS; ++it) {
        if (has_e) sk_row<true ><<<NN / 4, 256, 0, stream>>>(Mat, rc, rr);
        else       sk_row<false><<<NN / 4, 256, 0, stream>>>(Mat, rc, rr);
        if (has_e) sk_col<true ><<<gcol, 256, 0, stream>>>(Mat, rr, c_sum);
        else       sk_col<false><<<gcol, 256, 0, stream>>>(Mat, rr, c_sum);
        sk_recip<<<NN / 256, 256, 0, stream>>>(c_sum, rc);
    }

    dim3 gfin(4, NN);
    if (has_e) sk_final<true ><<<gfin, 256, 0, stream>>>(Mat, rr, rc, out);
    else       sk_final<false><<<gfin, 256, 0, stream>>>(Mat, rr, rc, out);
}